// Round 15
// baseline (196.599 us; speedup 1.0000x reference)
//
#include <hip/hip_runtime.h>

#define NN 4096     // nodes
#define HC 8        // heads
#define DC 32       // dim per head
#define OC 256      // out channels = HC*DC
#define KC 256      // in channels
#define CF 6        // curvature features

typedef _Float16 f16_t;
typedef f16_t f16x2 __attribute__((ext_vector_type(2)));
typedef f16_t f16x8 __attribute__((ext_vector_type(8)));
typedef float f32x4 __attribute__((ext_vector_type(4)));
typedef float f32x2 __attribute__((ext_vector_type(2)));
typedef unsigned u32x4 __attribute__((ext_vector_type(4)));

union HU { f16x2 h; unsigned u; };

// ---------------------------------------------------------------------------
// Kernel 1: heterogeneous prep. R25: role CHECKERBOARD + pack TLP x2.
// Budget analysis (R23/R24): total 185.7 = attn 80 + ~105 gap; R17/R18
// split-vs-monolith showed prep collectively ~100us vs a ~20us roofline
// (64MB adj ~10us HBM + small GEMM ~5-10us). Theory: front-loaded role
// blocks (gemm 0..511, pack 512+) land on disjoint CUs and the roles
// serialize by resource; pack's 32-deep serial ballot chains cap TLP.
// Fix: bid%9==0 -> gemm (exactly 512 of 4608), else pack (4096 blocks,
// 16 segments/wave instead of 32) — every CU co-hosts HBM-bound pack and
// VALU-bound gemm for the whole prep window, and the 64MB read gets 2x
// the waves. Roles write disjoint buffers; order within prep irrelevant.
// ---------------------------------------------------------------------------
__global__ __launch_bounds__(256) void prep_all(const float* __restrict__ x,
                                                const float* __restrict__ W,
                                                const float* __restrict__ a_l,
                                                const float* __restrict__ a_r,
                                                const int* __restrict__ adj,
                                                const float* __restrict__ cfeat,
                                                const float* __restrict__ Wc,
                                                const float* __restrict__ gate,
                                                float* __restrict__ e_l2,
                                                f16_t* __restrict__ erP,
                                                f16_t* __restrict__ hT2,
                                                unsigned* __restrict__ adjb,
                                                float* __restrict__ cfT,
                                                f16_t* __restrict__ cfP,
                                                float* __restrict__ Wc2) {
  __shared__ float As[16][68];   // [k][i]
  __shared__ float Bs[16][36];   // [k][c]
  __shared__ float Ct[DC][65];   // [c][i]
  const float LOG2E = 1.44269504088896340736f;
  const int t = threadIdx.x;
  const int bid = blockIdx.x;

  if (bid % 9 != 0) {
    // ---------------- pack role (4096 blocks interleaved) ----------------
    const int pb = bid - bid / 9 - 1;            // 0..4095
    const int ptid = pb * 256 + t;
    const int lane = t & 63;
    const int wv = pb * 4 + (t >> 6);            // 0..16383
    int v[16];
#pragma unroll
    for (int u = 0; u < 16; ++u) {
      int g = wv * 16 + u;                       // segment id 0..262143
      v[u] = adj[(size_t)(g >> 6) * NN + (g & 63) * 64 + lane];
    }
#pragma unroll
    for (int u = 0; u < 16; ++u) {
      int g = wv * 16 + u;
      unsigned long long m = __ballot(v[u] > 0);
      if (lane == 0) *(unsigned long long*)(adjb + (g >> 6) * 128 + (g & 63) * 2) = m;
    }
    if (ptid < NN * CF) {
      int j = ptid / CF, f = ptid - j * CF;
      float vv = cfeat[ptid];
      cfT[f * NN + j] = vv;
      int cc = j >> 5, qq = (j >> 3) & 3, tt = j & 7;
      cfP[((cc * 4 + qq) * CF + f) * 8 + tt] = (f16_t)vv;
    }
    if (ptid < HC * CF) Wc2[ptid] = Wc[ptid] * gate[0] * LOG2E;
    return;
  }

  // ---------------- gemm role (512 blocks interleaved) ----------------
  const int gid = bid / 9;       // 0..511
  const int i0 = (gid & 63) * 64;
  const int head = gid >> 6;
  const int c0 = head * DC;
  const int tx = t & 7;          // col group (4 cols)
  const int ty = t >> 3;         // row pair (2 rows)
  const int lr = t >> 2;         // staging row 0..63
  const int lk = (t & 3) * 4;    // staging k 0,4,8,12

  float acc[2][4] = {};
  f32x4 av = *(const f32x4*)&x[(size_t)(i0 + lr) * KC + lk];
  f32x4 wv = {};
  if (t < 128) wv = *(const f32x4*)&W[(size_t)(c0 + (t >> 2)) * KC + lk];
  for (int kk = 0; kk < KC; kk += 16) {
    __syncthreads();             // prev compute done before LDS overwrite
    As[lk + 0][lr] = av[0]; As[lk + 1][lr] = av[1];
    As[lk + 2][lr] = av[2]; As[lk + 3][lr] = av[3];
    if (t < 128) {
      int br = t >> 2;
      Bs[lk + 0][br] = wv[0]; Bs[lk + 1][br] = wv[1];
      Bs[lk + 2][br] = wv[2]; Bs[lk + 3][br] = wv[3];
    }
    __syncthreads();
    if (kk + 16 < KC) {          // prefetch next tile; latency hidden by FMAs
      av = *(const f32x4*)&x[(size_t)(i0 + lr) * KC + kk + 16 + lk];
      if (t < 128) wv = *(const f32x4*)&W[(size_t)(c0 + (t >> 2)) * KC + kk + 16 + lk];
    }
#pragma unroll
    for (int k = 0; k < 16; ++k) {
      f32x2 a = *(const f32x2*)&As[k][ty * 2];
      f32x4 b = *(const f32x4*)&Bs[k][tx * 4];
#pragma unroll
      for (int r = 0; r < 2; ++r)
#pragma unroll
        for (int u = 0; u < 4; ++u)
          acc[r][u] += a[r] * b[u];
    }
  }

  // e_l (f32 [i][h]) / e_r (packed f16, attn lane order); reduce across tx
  f32x4 al4 = *(const f32x4*)&a_l[c0 + tx * 4];
  f32x4 ar4 = *(const f32x4*)&a_r[c0 + tx * 4];
#pragma unroll
  for (int r = 0; r < 2; ++r) {
    float el = acc[r][0] * al4[0] + acc[r][1] * al4[1] +
               acc[r][2] * al4[2] + acc[r][3] * al4[3];
    float er = acc[r][0] * ar4[0] + acc[r][1] * ar4[1] +
               acc[r][2] * ar4[2] + acc[r][3] * ar4[3];
    el += __shfl_xor(el, 1, 64); el += __shfl_xor(el, 2, 64); el += __shfl_xor(el, 4, 64);
    er += __shfl_xor(er, 1, 64); er += __shfl_xor(er, 2, 64); er += __shfl_xor(er, 4, 64);
    if (tx == 0) {
      int j = i0 + ty * 2 + r;
      e_l2[j * HC + head] = el * LOG2E;
      int cc = j >> 5, qq = (j >> 3) & 3, tt = j & 7;
      erP[((cc * 4 + qq) * HC + head) * 8 + tt] = (f16_t)(er * LOG2E);
    }
  }

  // transpose to B-fragment layout via LDS; V stored f16
#pragma unroll
  for (int r = 0; r < 2; ++r)
#pragma unroll
    for (int u = 0; u < 4; ++u)
      Ct[tx * 4 + u][ty * 2 + r] = acc[r][u];
  __syncthreads();
  const size_t base = (size_t)head * (NN / 32) * 1024 + (size_t)(gid & 63) * 2048;
#pragma unroll
  for (int rep = 0; rep < 8; ++rep) {
    int idx = rep * 256 + t;                 // enumerates [chunkL][q][d][t8]
    int dd = (idx >> 3) & 31;
    int jl = (idx >> 10) * 32 + ((idx >> 8) & 3) * 8 + (idx & 7);
    hT2[base + idx] = (f16_t)Ct[dd][jl];
  }
}

// ---------------------------------------------------------------------------
// Kernel 2: fused masked attention. R24 body unchanged (banked: 80.0us,
// VGPR 64, no spill, VALUBusy 62%, zero bank conflicts; geometry lb(256,4)
// grid (256,4) proven optimal across the R19-R22 search; inline-asm f16 exp;
// S via MFMA ones-trick; mask folded as -inf into the bias chain).
// ---------------------------------------------------------------------------
__global__ __launch_bounds__(256, 4) void attn(const unsigned* __restrict__ adjb,
                                               const float* __restrict__ e_l2,
                                               const float* __restrict__ cfT,
                                               const float* __restrict__ Wc2,
                                               const u32x4* __restrict__ cfP4,
                                               const u32x4* __restrict__ erP4,
                                               const f16_t* __restrict__ hT2,
                                               float* __restrict__ out) {
  __shared__ float Obuf[16][64];
  __shared__ float Sbuf[16][2];
  const int tid = threadIdx.x;
  const int w = tid >> 6;        // 0..3: wave owns chunks c == w (mod 4)
  const int lane = tid & 63;
  const int il = lane & 15;
  const int quad = lane >> 4;
  const int ibase = blockIdx.x * 16;
  const int hg = blockIdx.y;     // head pair: heads hg*2, hg*2+1
  const int i = ibase + il;

  for (int idx = tid; idx < 16 * 64; idx += 256) (&Obuf[0][0])[idx] = 0.f;
  if (tid < 32) (&Sbuf[0][0])[tid] = 0.f;
  __syncthreads();

  // lane constants (f16x2 duplicated pairs)
  f16x2 cfi2h[CF];
#pragma unroll
  for (int f = 0; f < CF; ++f) {
    f16_t v = (f16_t)cfT[f * NN + i];
    cfi2h[f] = (f16x2){v, v};
  }
  f16x2 elh[2];
  {
    f32x2 e0 = *(const f32x2*)&e_l2[i * HC + hg * 2];
#pragma unroll
    for (int u = 0; u < 2; ++u) { f16_t v = (f16_t)e0[u]; elh[u] = (f16x2){v, v}; }
  }
  f16x2 wch[2][CF];
#pragma unroll
  for (int h = 0; h < 2; ++h)
#pragma unroll
    for (int f = 0; f < CF; ++f) {
      f16_t v = (f16_t)Wc2[(hg * 2 + h) * CF + f];
      wch[h][f] = (f16x2){v, v};
    }
  const f16x2 lslope = (f16x2){(f16_t)0.2f, (f16_t)0.2f};
  const f16x8 onesB = {(f16_t)1.f, (f16_t)1.f, (f16_t)1.f, (f16_t)1.f,
                       (f16_t)1.f, (f16_t)1.f, (f16_t)1.f, (f16_t)1.f};

  f32x4 acc[2][2];
#pragma unroll
  for (int h = 0; h < 2; ++h)
#pragma unroll
    for (int d = 0; d < 2; ++d) acc[h][d] = (f32x4){0.f, 0.f, 0.f, 0.f};
  f32x4 Sacc[2];
#pragma unroll
  for (int h = 0; h < 2; ++h) Sacc[h] = (f32x4){0.f, 0.f, 0.f, 0.f};

  const f16_t* hTbase = hT2 + (size_t)hg * 2 * ((NN / 32) * 1024) + quad * 256 + il * 8;
  const u32x4* cfb = cfP4 + quad * CF;           // c-stride 4*CF  (u32x4 units)
  const u32x4* erb = erP4 + quad * HC + hg * 2;  // c-stride 4*HC
  const unsigned* adjrow = adjb + i * 128;

  // ---- prime the prefetch registers for chunk c = w ----
  u32x4 cfc[CF];
#pragma unroll
  for (int f = 0; f < CF; ++f) cfc[f] = cfb[w * (4 * CF) + f];
  u32x4 erc[2];
#pragma unroll
  for (int h = 0; h < 2; ++h) erc[h] = erb[w * (4 * HC) + h];
  unsigned mc = adjrow[w];

#pragma unroll 2
  for (int c = w; c < NN / 32; c += 4) {
    // V fragments: issued at body top, consumed at the end (~full-body lead)
    const f16_t* bp0 = hTbase + c * 1024;
    const f16_t* bp1 = bp0 + (NN / 32) * 1024;
    f16x8 b00 = *(const f16x8*)bp0;
    f16x8 b01 = *(const f16x8*)(bp0 + 128);
    f16x8 b10 = *(const f16x8*)bp1;
    f16x8 b11 = *(const f16x8*)(bp1 + 128);

    const unsigned m8 = (mc >> (quad * 8)) & 0xffu;

    // ---- phase 1: args (consumes cfc/erc/m8; all pk-f16) ----
    f16x2 arg[2][4];
#pragma unroll
    for (int p = 0; p < 4; ++p) {
      // mask folded into bias init: masked j -> -inf (exp_f16(-inf) == +0)
      HU mb;
      mb.u = (((m8 >> (2 * p)) & 1u) ? 0u : 0xFC00u) |
             (((m8 >> (2 * p + 1)) & 1u) ? 0u : 0xFC000000u);
      f16x2 bias0 = mb.h;
      f16x2 bias1 = mb.h;
#pragma unroll
      for (int f = 0; f < CF; ++f) {
        HU cu; cu.u = cfc[f][p];
        f16x2 d = cfi2h[f] - cu.h;                       // v_pk_sub_f16
        f16x2 ad = __builtin_elementwise_max(d, -d);     // v_pk_max_f16 (neg mod)
        bias0 = __builtin_elementwise_fma(ad, wch[0][f], bias0);
        bias1 = __builtin_elementwise_fma(ad, wch[1][f], bias1);
      }
#pragma unroll
      for (int h = 0; h < 2; ++h) {
        HU eu; eu.u = erc[h][p];
        f16x2 s = elh[h] + eu.h;                         // v_pk_add_f16
        f16x2 lk = __builtin_elementwise_max(s, lslope * s);
        arg[h][p] = lk + (h ? bias1 : bias0);
      }
    }

    // ---- prefetch chunk c+4 (cfc/erc/mc all consumed; one body of lead) ----
    {
      const int cn = (c + 4) & (NN / 32 - 1);
#pragma unroll
      for (int f = 0; f < CF; ++f) cfc[f] = cfb[cn * (4 * CF) + f];
#pragma unroll
      for (int h = 0; h < 2; ++h) erc[h] = erb[cn * (4 * HC) + h];
      mc = adjrow[cn];
    }

    // ---- phase 2: inline-asm f16 exp (VOP1 lo; lshr for hi; pack) ----
    union { f16x8 v; unsigned u[4]; } af[2];
#pragma unroll
    for (int p = 0; p < 4; ++p) {
#pragma unroll
      for (int h = 0; h < 2; ++h) {
        HU au; au.h = arg[h][p];
        unsigned hiu = au.u >> 16;
        unsigned r0, r1, pk;
        asm("v_exp_f16 %0, %1" : "=v"(r0) : "v"(au.u));
        asm("v_exp_f16 %0, %1" : "=v"(r1) : "v"(hiu));
        asm("v_pack_b32_f16 %0, %1, %2" : "=v"(pk) : "v"(r0), "v"(r1));
        af[h].u[p] = pk;
      }
    }

#pragma unroll
    for (int h = 0; h < 2; ++h) {
      acc[h][0] = __builtin_amdgcn_mfma_f32_16x16x32_f16(af[h].v, h ? b10 : b00, acc[h][0], 0, 0, 0);
      acc[h][1] = __builtin_amdgcn_mfma_f32_16x16x32_f16(af[h].v, h ? b11 : b01, acc[h][1], 0, 0, 0);
      Sacc[h] = __builtin_amdgcn_mfma_f32_16x16x32_f16(af[h].v, onesB, Sacc[h], 0, 0, 0);
    }
  }

  // S: D[row=quad*4+r][col] = chunk row-sum (identical across cols) ->
  // one lane per quad contributes each row
  if (il == 0) {
#pragma unroll
    for (int h = 0; h < 2; ++h)
#pragma unroll
      for (int r = 0; r < 4; ++r)
        atomicAdd(&Sbuf[quad * 4 + r][h], Sacc[h][r]);
  }
  // accumulate O partials: C/D layout row = quad*4+r (i), col = il (d half)
#pragma unroll
  for (int h = 0; h < 2; ++h)
#pragma unroll
    for (int dh = 0; dh < 2; ++dh)
#pragma unroll
      for (int r = 0; r < 4; ++r)
        atomicAdd(&Obuf[quad * 4 + r][h * DC + dh * 16 + il], acc[h][dh][r]);
  __syncthreads();

  // epilogue: divide by softmax denom, coalesced store
  for (int idx = tid; idx < 16 * 64; idx += 256) {
    int row = idx >> 6;
    int colg = idx & 63;
    out[(size_t)(ibase + row) * OC + hg * 64 + colg] =
        Obuf[row][colg] / Sbuf[row][colg >> 5];
  }
}

// ---------------------------------------------------------------------------
extern "C" void kernel_launch(void* const* d_in, const int* in_sizes, int n_in,
                              void* d_out, int out_size, void* d_ws, size_t ws_size,
                              hipStream_t stream) {
  const float* x    = (const float*)d_in[0];
  // d_in[1] = positions — unused by the reference
  const float* cfeat= (const float*)d_in[2];
  const int*   adj  = (const int*)d_in[3];
  const float* W    = (const float*)d_in[4];
  const float* a_l  = (const float*)d_in[5];
  const float* a_r  = (const float*)d_in[6];
  const float* Wc   = (const float*)d_in[7];
  const float* gate = (const float*)d_in[8];
  float* out = (float*)d_out;

  char* ws = (char*)d_ws;
  f16_t*    hT2  = (f16_t*)ws;                               // 2 MB
  unsigned* adjb = (unsigned*)(ws + (2u << 20));             // 2 MB
  float*    e_l2 = (float*)(ws + (4u << 20));                // 128 KB
  float*    cfT  = (float*)(ws + (4u << 20) + (128u << 10)); // 96 KB
  float*    Wc2  = (float*)(ws + (4u << 20) + (256u << 10)); // 192 B
  f16_t*    cfP  = (f16_t*)(ws + (4u << 20) + (320u << 10)); // 48 KB
  f16_t*    erP  = (f16_t*)(ws + (4u << 20) + (384u << 10)); // 64 KB

  prep_all<<<4608, 256, 0, stream>>>(x, W, a_l, a_r, adj, cfeat, Wc, gate,
                                     e_l2, erP, hT2, adjb, cfT, cfP, Wc2);
  attn<<<dim3(NN / 16, 4), 256, 0, stream>>>(adjb, e_l2, cfT, Wc2,
                                             (const u32x4*)cfP, (const u32x4*)erP,
                                             hT2, out);
}

// Round 17
// 188.140 us; speedup vs baseline: 1.0450x; 1.0450x over previous
//
#include <hip/hip_runtime.h>

#define NN 4096     // nodes
#define HC 8        // heads
#define DC 32       // dim per head
#define OC 256      // out channels = HC*DC
#define KC 256      // in channels
#define CF 6        // curvature features

typedef _Float16 f16_t;
typedef f16_t f16x2 __attribute__((ext_vector_type(2)));
typedef f16_t f16x8 __attribute__((ext_vector_type(8)));
typedef float f32x4 __attribute__((ext_vector_type(4)));
typedef float f32x2 __attribute__((ext_vector_type(2)));
typedef unsigned u32x4 __attribute__((ext_vector_type(4)));

union HU { f16x2 h; unsigned u; };

// ---------------------------------------------------------------------------
// Kernel 1: heterogeneous prep (monolith, front-loaded roles — R25's
// checkerboard regressed −11us; R26's cooperative fusion never launched
// (hipLaunchCooperativeKernel fails under the harness's graph capture:
// absmax == max|ref| proved out stayed memset-zero)).
// R27 trim: pack role at 1024 blocks (was 2048), 64 segments/wave in 4
// batched rounds of 16 — ramp cost is ~190 blocks/us (R25-calibrated), so
// prep grid 2560 -> 1536 saves ~5us; HBM-bound pack (64MB ~= 10us floor)
// keeps full TLP (4096 waves x 16 outstanding loads).
// Blocks 0..511 (gemm role): h-GEMM (64 rows x 1 head) + e_l (f32 [i][h]) +
//   e_r packed f16 in attn lane order (erP, pre-scaled LOG2E) + V as f16 in
//   attn's B-fragment order (hT2[head][c][q][d32][t8]). Cross-tile global
//   prefetch kept.
// Blocks 512..1535 (pack role): ballot-pack adj -> 2MB bitmask; cfT (f32,
//   i-side) + cfP packed f16 (cfP[c][q][f][t8]); Wc2 = Wc*gate*LOG2E.
// ---------------------------------------------------------------------------
__global__ __launch_bounds__(256) void prep_all(const float* __restrict__ x,
                                                const float* __restrict__ W,
                                                const float* __restrict__ a_l,
                                                const float* __restrict__ a_r,
                                                const int* __restrict__ adj,
                                                const float* __restrict__ cfeat,
                                                const float* __restrict__ Wc,
                                                const float* __restrict__ gate,
                                                float* __restrict__ e_l2,
                                                f16_t* __restrict__ erP,
                                                f16_t* __restrict__ hT2,
                                                unsigned* __restrict__ adjb,
                                                float* __restrict__ cfT,
                                                f16_t* __restrict__ cfP,
                                                float* __restrict__ Wc2) {
  __shared__ float As[16][68];   // [k][i]
  __shared__ float Bs[16][36];   // [k][c]
  __shared__ float Ct[DC][65];   // [c][i]
  const float LOG2E = 1.44269504088896340736f;
  const int t = threadIdx.x;
  const int bid = blockIdx.x;

  if (bid >= 512) {
    // ---------------- pack role (1024 blocks; 64 segs/wave) ----------------
    const int pb = bid - 512;                    // 0..1023
    const int ptid = pb * 256 + t;
    const int lane = t & 63;
    const int wv = pb * 4 + (t >> 6);            // 0..4095
    for (int rr = 0; rr < 4; ++rr) {
      int v[16];
#pragma unroll
      for (int u = 0; u < 16; ++u) {
        int g = wv * 64 + rr * 16 + u;           // segment id 0..262143
        v[u] = adj[(size_t)(g >> 6) * NN + (g & 63) * 64 + lane];
      }
#pragma unroll
      for (int u = 0; u < 16; ++u) {
        int g = wv * 64 + rr * 16 + u;
        unsigned long long m = __ballot(v[u] > 0);
        if (lane == 0) *(unsigned long long*)(adjb + (g >> 6) * 128 + (g & 63) * 2) = m;
      }
    }
    if (ptid < NN * CF) {
      int j = ptid / CF, f = ptid - j * CF;
      float vv = cfeat[ptid];
      cfT[f * NN + j] = vv;
      int cc = j >> 5, qq = (j >> 3) & 3, tt = j & 7;
      cfP[((cc * 4 + qq) * CF + f) * 8 + tt] = (f16_t)vv;
    }
    if (ptid < HC * CF) Wc2[ptid] = Wc[ptid] * gate[0] * LOG2E;
    return;
  }

  // ---------------- gemm role ----------------
  const int i0 = (bid & 63) * 64;
  const int head = bid >> 6;
  const int c0 = head * DC;
  const int tx = t & 7;          // col group (4 cols)
  const int ty = t >> 3;         // row pair (2 rows)
  const int lr = t >> 2;         // staging row 0..63
  const int lk = (t & 3) * 4;    // staging k 0,4,8,12

  float acc[2][4] = {};
  f32x4 av = *(const f32x4*)&x[(size_t)(i0 + lr) * KC + lk];
  f32x4 wv = {};
  if (t < 128) wv = *(const f32x4*)&W[(size_t)(c0 + (t >> 2)) * KC + lk];
  for (int kk = 0; kk < KC; kk += 16) {
    __syncthreads();             // prev compute done before LDS overwrite
    As[lk + 0][lr] = av[0]; As[lk + 1][lr] = av[1];
    As[lk + 2][lr] = av[2]; As[lk + 3][lr] = av[3];
    if (t < 128) {
      int br = t >> 2;
      Bs[lk + 0][br] = wv[0]; Bs[lk + 1][br] = wv[1];
      Bs[lk + 2][br] = wv[2]; Bs[lk + 3][br] = wv[3];
    }
    __syncthreads();
    if (kk + 16 < KC) {          // prefetch next tile; latency hidden by FMAs
      av = *(const f32x4*)&x[(size_t)(i0 + lr) * KC + kk + 16 + lk];
      if (t < 128) wv = *(const f32x4*)&W[(size_t)(c0 + (t >> 2)) * KC + kk + 16 + lk];
    }
#pragma unroll
    for (int k = 0; k < 16; ++k) {
      f32x2 a = *(const f32x2*)&As[k][ty * 2];
      f32x4 b = *(const f32x4*)&Bs[k][tx * 4];
#pragma unroll
      for (int r = 0; r < 2; ++r)
#pragma unroll
        for (int u = 0; u < 4; ++u)
          acc[r][u] += a[r] * b[u];
    }
  }

  // e_l (f32 [i][h]) / e_r (packed f16, attn lane order); reduce across tx
  f32x4 al4 = *(const f32x4*)&a_l[c0 + tx * 4];
  f32x4 ar4 = *(const f32x4*)&a_r[c0 + tx * 4];
#pragma unroll
  for (int r = 0; r < 2; ++r) {
    float el = acc[r][0] * al4[0] + acc[r][1] * al4[1] +
               acc[r][2] * al4[2] + acc[r][3] * al4[3];
    float er = acc[r][0] * ar4[0] + acc[r][1] * ar4[1] +
               acc[r][2] * ar4[2] + acc[r][3] * ar4[3];
    el += __shfl_xor(el, 1, 64); el += __shfl_xor(el, 2, 64); el += __shfl_xor(el, 4, 64);
    er += __shfl_xor(er, 1, 64); er += __shfl_xor(er, 2, 64); er += __shfl_xor(er, 4, 64);
    if (tx == 0) {
      int j = i0 + ty * 2 + r;
      e_l2[j * HC + head] = el * LOG2E;
      int cc = j >> 5, qq = (j >> 3) & 3, tt = j & 7;
      erP[((cc * 4 + qq) * HC + head) * 8 + tt] = (f16_t)(er * LOG2E);
    }
  }

  // transpose to B-fragment layout via LDS; V stored f16
#pragma unroll
  for (int r = 0; r < 2; ++r)
#pragma unroll
    for (int u = 0; u < 4; ++u)
      Ct[tx * 4 + u][ty * 2 + r] = acc[r][u];
  __syncthreads();
  const size_t base = (size_t)head * (NN / 32) * 1024 + (size_t)(bid & 63) * 2048;
#pragma unroll
  for (int rep = 0; rep < 8; ++rep) {
    int idx = rep * 256 + t;                 // enumerates [chunkL][q][d][t8]
    int dd = (idx >> 3) & 31;
    int jl = (idx >> 10) * 32 + ((idx >> 8) & 3) * 8 + (idx & 7);
    hT2[base + idx] = (f16_t)Ct[dd][jl];
  }
}

// ---------------------------------------------------------------------------
// Kernel 2: fused masked attention. R24 body unchanged (banked best: attn
// 79.4-80.0us, VGPR 64, no spill, VALUBusy ~62%, zero bank conflicts;
// geometry lb(256,4) grid (256,4) proven optimal across the R19-R22 search;
// inline-asm f16 exp; S via MFMA ones-trick; mask folded as -inf into the
// bias chain; cross-iteration register prefetch).
// ---------------------------------------------------------------------------
__global__ __launch_bounds__(256, 4) void attn(const unsigned* __restrict__ adjb,
                                               const float* __restrict__ e_l2,
                                               const float* __restrict__ cfT,
                                               const float* __restrict__ Wc2,
                                               const u32x4* __restrict__ cfP4,
                                               const u32x4* __restrict__ erP4,
                                               const f16_t* __restrict__ hT2,
                                               float* __restrict__ out) {
  __shared__ float Obuf[16][64];
  __shared__ float Sbuf[16][2];
  const int tid = threadIdx.x;
  const int w = tid >> 6;        // 0..3: wave owns chunks c == w (mod 4)
  const int lane = tid & 63;
  const int il = lane & 15;
  const int quad = lane >> 4;
  const int ibase = blockIdx.x * 16;
  const int hg = blockIdx.y;     // head pair: heads hg*2, hg*2+1
  const int i = ibase + il;

  for (int idx = tid; idx < 16 * 64; idx += 256) (&Obuf[0][0])[idx] = 0.f;
  if (tid < 32) (&Sbuf[0][0])[tid] = 0.f;
  __syncthreads();

  // lane constants (f16x2 duplicated pairs)
  f16x2 cfi2h[CF];
#pragma unroll
  for (int f = 0; f < CF; ++f) {
    f16_t v = (f16_t)cfT[f * NN + i];
    cfi2h[f] = (f16x2){v, v};
  }
  f16x2 elh[2];
  {
    f32x2 e0 = *(const f32x2*)&e_l2[i * HC + hg * 2];
#pragma unroll
    for (int u = 0; u < 2; ++u) { f16_t v = (f16_t)e0[u]; elh[u] = (f16x2){v, v}; }
  }
  f16x2 wch[2][CF];
#pragma unroll
  for (int h = 0; h < 2; ++h)
#pragma unroll
    for (int f = 0; f < CF; ++f) {
      f16_t v = (f16_t)Wc2[(hg * 2 + h) * CF + f];
      wch[h][f] = (f16x2){v, v};
    }
  const f16x2 lslope = (f16x2){(f16_t)0.2f, (f16_t)0.2f};
  const f16x8 onesB = {(f16_t)1.f, (f16_t)1.f, (f16_t)1.f, (f16_t)1.f,
                       (f16_t)1.f, (f16_t)1.f, (f16_t)1.f, (f16_t)1.f};

  f32x4 acc[2][2];
#pragma unroll
  for (int h = 0; h < 2; ++h)
#pragma unroll
    for (int d = 0; d < 2; ++d) acc[h][d] = (f32x4){0.f, 0.f, 0.f, 0.f};
  f32x4 Sacc[2];
#pragma unroll
  for (int h = 0; h < 2; ++h) Sacc[h] = (f32x4){0.f, 0.f, 0.f, 0.f};

  const f16_t* hTbase = hT2 + (size_t)hg * 2 * ((NN / 32) * 1024) + quad * 256 + il * 8;
  const u32x4* cfb = cfP4 + quad * CF;           // c-stride 4*CF  (u32x4 units)
  const u32x4* erb = erP4 + quad * HC + hg * 2;  // c-stride 4*HC
  const unsigned* adjrow = adjb + i * 128;

  // ---- prime the prefetch registers for chunk c = w ----
  u32x4 cfc[CF];
#pragma unroll
  for (int f = 0; f < CF; ++f) cfc[f] = cfb[w * (4 * CF) + f];
  u32x4 erc[2];
#pragma unroll
  for (int h = 0; h < 2; ++h) erc[h] = erb[w * (4 * HC) + h];
  unsigned mc = adjrow[w];

#pragma unroll 2
  for (int c = w; c < NN / 32; c += 4) {
    // V fragments: issued at body top, consumed at the end (~full-body lead)
    const f16_t* bp0 = hTbase + c * 1024;
    const f16_t* bp1 = bp0 + (NN / 32) * 1024;
    f16x8 b00 = *(const f16x8*)bp0;
    f16x8 b01 = *(const f16x8*)(bp0 + 128);
    f16x8 b10 = *(const f16x8*)bp1;
    f16x8 b11 = *(const f16x8*)(bp1 + 128);

    const unsigned m8 = (mc >> (quad * 8)) & 0xffu;

    // ---- phase 1: args (consumes cfc/erc/m8; all pk-f16) ----
    f16x2 arg[2][4];
#pragma unroll
    for (int p = 0; p < 4; ++p) {
      // mask folded into bias init: masked j -> -inf (exp_f16(-inf) == +0)
      HU mb;
      mb.u = (((m8 >> (2 * p)) & 1u) ? 0u : 0xFC00u) |
             (((m8 >> (2 * p + 1)) & 1u) ? 0u : 0xFC000000u);
      f16x2 bias0 = mb.h;
      f16x2 bias1 = mb.h;
#pragma unroll
      for (int f = 0; f < CF; ++f) {
        HU cu; cu.u = cfc[f][p];
        f16x2 d = cfi2h[f] - cu.h;                       // v_pk_sub_f16
        f16x2 ad = __builtin_elementwise_max(d, -d);     // v_pk_max_f16 (neg mod)
        bias0 = __builtin_elementwise_fma(ad, wch[0][f], bias0);
        bias1 = __builtin_elementwise_fma(ad, wch[1][f], bias1);
      }
#pragma unroll
      for (int h = 0; h < 2; ++h) {
        HU eu; eu.u = erc[h][p];
        f16x2 s = elh[h] + eu.h;                         // v_pk_add_f16
        f16x2 lk = __builtin_elementwise_max(s, lslope * s);
        arg[h][p] = lk + (h ? bias1 : bias0);
      }
    }

    // ---- prefetch chunk c+4 (cfc/erc/mc all consumed; one body of lead) ----
    {
      const int cn = (c + 4) & (NN / 32 - 1);
#pragma unroll
      for (int f = 0; f < CF; ++f) cfc[f] = cfb[cn * (4 * CF) + f];
#pragma unroll
      for (int h = 0; h < 2; ++h) erc[h] = erb[cn * (4 * HC) + h];
      mc = adjrow[cn];
    }

    // ---- phase 2: inline-asm f16 exp (VOP1 lo; lshr for hi; pack) ----
    union { f16x8 v; unsigned u[4]; } af[2];
#pragma unroll
    for (int p = 0; p < 4; ++p) {
#pragma unroll
      for (int h = 0; h < 2; ++h) {
        HU au; au.h = arg[h][p];
        unsigned hiu = au.u >> 16;
        unsigned r0, r1, pk;
        asm("v_exp_f16 %0, %1" : "=v"(r0) : "v"(au.u));
        asm("v_exp_f16 %0, %1" : "=v"(r1) : "v"(hiu));
        asm("v_pack_b32_f16 %0, %1, %2" : "=v"(pk) : "v"(r0), "v"(r1));
        af[h].u[p] = pk;
      }
    }

#pragma unroll
    for (int h = 0; h < 2; ++h) {
      acc[h][0] = __builtin_amdgcn_mfma_f32_16x16x32_f16(af[h].v, h ? b10 : b00, acc[h][0], 0, 0, 0);
      acc[h][1] = __builtin_amdgcn_mfma_f32_16x16x32_f16(af[h].v, h ? b11 : b01, acc[h][1], 0, 0, 0);
      Sacc[h] = __builtin_amdgcn_mfma_f32_16x16x32_f16(af[h].v, onesB, Sacc[h], 0, 0, 0);
    }
  }

  // S: D[row=quad*4+r][col] = chunk row-sum (identical across cols) ->
  // one lane per quad contributes each row
  if (il == 0) {
#pragma unroll
    for (int h = 0; h < 2; ++h)
#pragma unroll
      for (int r = 0; r < 4; ++r)
        atomicAdd(&Sbuf[quad * 4 + r][h], Sacc[h][r]);
  }
  // accumulate O partials: C/D layout row = quad*4+r (i), col = il (d half)
#pragma unroll
  for (int h = 0; h < 2; ++h)
#pragma unroll
    for (int dh = 0; dh < 2; ++dh)
#pragma unroll
      for (int r = 0; r < 4; ++r)
        atomicAdd(&Obuf[quad * 4 + r][h * DC + dh * 16 + il], acc[h][dh][r]);
  __syncthreads();

  // epilogue: divide by softmax denom, coalesced store
  for (int idx = tid; idx < 16 * 64; idx += 256) {
    int row = idx >> 6;
    int colg = idx & 63;
    out[(size_t)(ibase + row) * OC + hg * 64 + colg] =
        Obuf[row][colg] / Sbuf[row][colg >> 5];
  }
}

// ---------------------------------------------------------------------------
extern "C" void kernel_launch(void* const* d_in, const int* in_sizes, int n_in,
                              void* d_out, int out_size, void* d_ws, size_t ws_size,
                              hipStream_t stream) {
  const float* x    = (const float*)d_in[0];
  // d_in[1] = positions — unused by the reference
  const float* cfeat= (const float*)d_in[2];
  const int*   adj  = (const int*)d_in[3];
  const float* W    = (const float*)d_in[4];
  const float* a_l  = (const float*)d_in[5];
  const float* a_r  = (const float*)d_in[6];
  const float* Wc   = (const float*)d_in[7];
  const float* gate = (const float*)d_in[8];
  float* out = (float*)d_out;

  char* ws = (char*)d_ws;
  f16_t*    hT2  = (f16_t*)ws;                               // 2 MB
  unsigned* adjb = (unsigned*)(ws + (2u << 20));             // 2 MB
  float*    e_l2 = (float*)(ws + (4u << 20));                // 128 KB
  float*    cfT  = (float*)(ws + (4u << 20) + (128u << 10)); // 96 KB
  float*    Wc2  = (float*)(ws + (4u << 20) + (256u << 10)); // 192 B
  f16_t*    cfP  = (f16_t*)(ws + (4u << 20) + (320u << 10)); // 48 KB
  f16_t*    erP  = (f16_t*)(ws + (4u << 20) + (384u << 10)); // 64 KB

  prep_all<<<1536, 256, 0, stream>>>(x, W, a_l, a_r, adj, cfeat, Wc, gate,
                                     e_l2, erP, hT2, adjb, cfT, cfP, Wc2);
  attn<<<dim3(NN / 16, 4), 256, 0, stream>>>(adjb, e_l2, cfT, Wc2,
                                             (const u32x4*)cfP, (const u32x4*)erP,
                                             hT2, out);
}

// Round 18
// 184.709 us; speedup vs baseline: 1.0644x; 1.0186x over previous
//
#include <hip/hip_runtime.h>

#define NN 4096     // nodes
#define HC 8        // heads
#define DC 32       // dim per head
#define OC 256      // out channels = HC*DC
#define KC 256      // in channels
#define CF 6        // curvature features

typedef _Float16 f16_t;
typedef f16_t f16x2 __attribute__((ext_vector_type(2)));
typedef f16_t f16x8 __attribute__((ext_vector_type(8)));
typedef float f32x4 __attribute__((ext_vector_type(4)));
typedef float f32x2 __attribute__((ext_vector_type(2)));
typedef unsigned u32x4 __attribute__((ext_vector_type(4)));

union HU { f16x2 h; unsigned u; };

// ---------------------------------------------------------------------------
// Kernel 1: heterogeneous prep — EXACT R23 configuration (measured best
// total 185.1us). R27's 1024-block pack trim regressed (+3us: TLP loss on
// the 64MB read > ramp saving); R25's checkerboard regressed (-11us); R26's
// cooperative fusion doesn't launch under graph capture. 2560 blocks:
// Blocks 0..511 (gemm role): h-GEMM (64 rows x 1 head) + e_l (f32 [i][h]) +
//   e_r packed f16 in attn lane order (erP, pre-scaled LOG2E) + V as f16 in
//   attn's B-fragment order (hT2[head][c][q][d32][t8]). Cross-tile global
//   prefetch kept.
// Blocks 512..2559 (pack role): ballot-pack adj -> 2MB bitmask (32 batched
//   loads in flight before the ballot chain); cfT (f32, i-side) + cfP
//   packed f16 (cfP[c][q][f][t8]); Wc2 = Wc*gate*LOG2E.
// ---------------------------------------------------------------------------
__global__ __launch_bounds__(256) void prep_all(const float* __restrict__ x,
                                                const float* __restrict__ W,
                                                const float* __restrict__ a_l,
                                                const float* __restrict__ a_r,
                                                const int* __restrict__ adj,
                                                const float* __restrict__ cfeat,
                                                const float* __restrict__ Wc,
                                                const float* __restrict__ gate,
                                                float* __restrict__ e_l2,
                                                f16_t* __restrict__ erP,
                                                f16_t* __restrict__ hT2,
                                                unsigned* __restrict__ adjb,
                                                float* __restrict__ cfT,
                                                f16_t* __restrict__ cfP,
                                                float* __restrict__ Wc2) {
  __shared__ float As[16][68];   // [k][i]
  __shared__ float Bs[16][36];   // [k][c]
  __shared__ float Ct[DC][65];   // [c][i]
  const float LOG2E = 1.44269504088896340736f;
  const int t = threadIdx.x;
  const int bid = blockIdx.x;

  if (bid >= 512) {
    // ---------------- pack role ----------------
    const int pb = bid - 512;                    // 0..2047
    const int ptid = pb * 256 + t;
    const int lane = t & 63;
    const int wv = pb * 4 + (t >> 6);            // 0..8191
    int v[32];
#pragma unroll
    for (int u = 0; u < 32; ++u) {
      int g = wv * 32 + u;                       // segment id
      v[u] = adj[(size_t)(g >> 6) * NN + (g & 63) * 64 + lane];
    }
#pragma unroll
    for (int u = 0; u < 32; ++u) {
      int g = wv * 32 + u;
      unsigned long long m = __ballot(v[u] > 0);
      if (lane == 0) *(unsigned long long*)(adjb + (g >> 6) * 128 + (g & 63) * 2) = m;
    }
    if (ptid < NN * CF) {
      int j = ptid / CF, f = ptid - j * CF;
      float vv = cfeat[ptid];
      cfT[f * NN + j] = vv;
      int cc = j >> 5, qq = (j >> 3) & 3, tt = j & 7;
      cfP[((cc * 4 + qq) * CF + f) * 8 + tt] = (f16_t)vv;
    }
    if (ptid < HC * CF) Wc2[ptid] = Wc[ptid] * gate[0] * LOG2E;
    return;
  }

  // ---------------- gemm role ----------------
  const int i0 = (bid & 63) * 64;
  const int head = bid >> 6;
  const int c0 = head * DC;
  const int tx = t & 7;          // col group (4 cols)
  const int ty = t >> 3;         // row pair (2 rows)
  const int lr = t >> 2;         // staging row 0..63
  const int lk = (t & 3) * 4;    // staging k 0,4,8,12

  float acc[2][4] = {};
  f32x4 av = *(const f32x4*)&x[(size_t)(i0 + lr) * KC + lk];
  f32x4 wv = {};
  if (t < 128) wv = *(const f32x4*)&W[(size_t)(c0 + (t >> 2)) * KC + lk];
  for (int kk = 0; kk < KC; kk += 16) {
    __syncthreads();             // prev compute done before LDS overwrite
    As[lk + 0][lr] = av[0]; As[lk + 1][lr] = av[1];
    As[lk + 2][lr] = av[2]; As[lk + 3][lr] = av[3];
    if (t < 128) {
      int br = t >> 2;
      Bs[lk + 0][br] = wv[0]; Bs[lk + 1][br] = wv[1];
      Bs[lk + 2][br] = wv[2]; Bs[lk + 3][br] = wv[3];
    }
    __syncthreads();
    if (kk + 16 < KC) {          // prefetch next tile; latency hidden by FMAs
      av = *(const f32x4*)&x[(size_t)(i0 + lr) * KC + kk + 16 + lk];
      if (t < 128) wv = *(const f32x4*)&W[(size_t)(c0 + (t >> 2)) * KC + kk + 16 + lk];
    }
#pragma unroll
    for (int k = 0; k < 16; ++k) {
      f32x2 a = *(const f32x2*)&As[k][ty * 2];
      f32x4 b = *(const f32x4*)&Bs[k][tx * 4];
#pragma unroll
      for (int r = 0; r < 2; ++r)
#pragma unroll
        for (int u = 0; u < 4; ++u)
          acc[r][u] += a[r] * b[u];
    }
  }

  // e_l (f32 [i][h]) / e_r (packed f16, attn lane order); reduce across tx
  f32x4 al4 = *(const f32x4*)&a_l[c0 + tx * 4];
  f32x4 ar4 = *(const f32x4*)&a_r[c0 + tx * 4];
#pragma unroll
  for (int r = 0; r < 2; ++r) {
    float el = acc[r][0] * al4[0] + acc[r][1] * al4[1] +
               acc[r][2] * al4[2] + acc[r][3] * al4[3];
    float er = acc[r][0] * ar4[0] + acc[r][1] * ar4[1] +
               acc[r][2] * ar4[2] + acc[r][3] * ar4[3];
    el += __shfl_xor(el, 1, 64); el += __shfl_xor(el, 2, 64); el += __shfl_xor(el, 4, 64);
    er += __shfl_xor(er, 1, 64); er += __shfl_xor(er, 2, 64); er += __shfl_xor(er, 4, 64);
    if (tx == 0) {
      int j = i0 + ty * 2 + r;
      e_l2[j * HC + head] = el * LOG2E;
      int cc = j >> 5, qq = (j >> 3) & 3, tt = j & 7;
      erP[((cc * 4 + qq) * HC + head) * 8 + tt] = (f16_t)(er * LOG2E);
    }
  }

  // transpose to B-fragment layout via LDS; V stored f16
#pragma unroll
  for (int r = 0; r < 2; ++r)
#pragma unroll
    for (int u = 0; u < 4; ++u)
      Ct[tx * 4 + u][ty * 2 + r] = acc[r][u];
  __syncthreads();
  const size_t base = (size_t)head * (NN / 32) * 1024 + (size_t)(bid & 63) * 2048;
#pragma unroll
  for (int rep = 0; rep < 8; ++rep) {
    int idx = rep * 256 + t;                 // enumerates [chunkL][q][d][t8]
    int dd = (idx >> 3) & 31;
    int jl = (idx >> 10) * 32 + ((idx >> 8) & 3) * 8 + (idx & 7);
    hT2[base + idx] = (f16_t)Ct[dd][jl];
  }
}

// ---------------------------------------------------------------------------
// Kernel 2: fused masked attention. R28 = banked R24 body with ONE variable:
// chunk loop unroll 2 -> 4 (an R13-era setting never re-tested after the
// body shrank). Theory: 38% VALU-idle at 4 waves/SIMD; per iteration ~13 L2
// loads (~200cy) are covered only by the same iteration's ~440 VALU cycles —
// unroll 4 lets iteration k+1's V-loads issue under k's exp/MFMA tail.
// Register headroom ample (64 of 128 cap; the spilling configs were all
// 512-thread). Proven pieces retained: lb(256,4) grid (256,4); inline-asm
// f16 exp; S via MFMA ones-trick; mask folded as -inf; cross-iter prefetch.
// Branch A: attn ~70-75us. Branch B: neutral -> plateau declared next round.
// Failure signal: WRITE >> 4MB or VGPR > 100 -> revert to unroll 2.
// ---------------------------------------------------------------------------
__global__ __launch_bounds__(256, 4) void attn(const unsigned* __restrict__ adjb,
                                               const float* __restrict__ e_l2,
                                               const float* __restrict__ cfT,
                                               const float* __restrict__ Wc2,
                                               const u32x4* __restrict__ cfP4,
                                               const u32x4* __restrict__ erP4,
                                               const f16_t* __restrict__ hT2,
                                               float* __restrict__ out) {
  __shared__ float Obuf[16][64];
  __shared__ float Sbuf[16][2];
  const int tid = threadIdx.x;
  const int w = tid >> 6;        // 0..3: wave owns chunks c == w (mod 4)
  const int lane = tid & 63;
  const int il = lane & 15;
  const int quad = lane >> 4;
  const int ibase = blockIdx.x * 16;
  const int hg = blockIdx.y;     // head pair: heads hg*2, hg*2+1
  const int i = ibase + il;

  for (int idx = tid; idx < 16 * 64; idx += 256) (&Obuf[0][0])[idx] = 0.f;
  if (tid < 32) (&Sbuf[0][0])[tid] = 0.f;
  __syncthreads();

  // lane constants (f16x2 duplicated pairs)
  f16x2 cfi2h[CF];
#pragma unroll
  for (int f = 0; f < CF; ++f) {
    f16_t v = (f16_t)cfT[f * NN + i];
    cfi2h[f] = (f16x2){v, v};
  }
  f16x2 elh[2];
  {
    f32x2 e0 = *(const f32x2*)&e_l2[i * HC + hg * 2];
#pragma unroll
    for (int u = 0; u < 2; ++u) { f16_t v = (f16_t)e0[u]; elh[u] = (f16x2){v, v}; }
  }
  f16x2 wch[2][CF];
#pragma unroll
  for (int h = 0; h < 2; ++h)
#pragma unroll
    for (int f = 0; f < CF; ++f) {
      f16_t v = (f16_t)Wc2[(hg * 2 + h) * CF + f];
      wch[h][f] = (f16x2){v, v};
    }
  const f16x2 lslope = (f16x2){(f16_t)0.2f, (f16_t)0.2f};
  const f16x8 onesB = {(f16_t)1.f, (f16_t)1.f, (f16_t)1.f, (f16_t)1.f,
                       (f16_t)1.f, (f16_t)1.f, (f16_t)1.f, (f16_t)1.f};

  f32x4 acc[2][2];
#pragma unroll
  for (int h = 0; h < 2; ++h)
#pragma unroll
    for (int d = 0; d < 2; ++d) acc[h][d] = (f32x4){0.f, 0.f, 0.f, 0.f};
  f32x4 Sacc[2];
#pragma unroll
  for (int h = 0; h < 2; ++h) Sacc[h] = (f32x4){0.f, 0.f, 0.f, 0.f};

  const f16_t* hTbase = hT2 + (size_t)hg * 2 * ((NN / 32) * 1024) + quad * 256 + il * 8;
  const u32x4* cfb = cfP4 + quad * CF;           // c-stride 4*CF  (u32x4 units)
  const u32x4* erb = erP4 + quad * HC + hg * 2;  // c-stride 4*HC
  const unsigned* adjrow = adjb + i * 128;

  // ---- prime the prefetch registers for chunk c = w ----
  u32x4 cfc[CF];
#pragma unroll
  for (int f = 0; f < CF; ++f) cfc[f] = cfb[w * (4 * CF) + f];
  u32x4 erc[2];
#pragma unroll
  for (int h = 0; h < 2; ++h) erc[h] = erb[w * (4 * HC) + h];
  unsigned mc = adjrow[w];

#pragma unroll 4
  for (int c = w; c < NN / 32; c += 4) {
    // V fragments: issued at body top, consumed at the end (~full-body lead)
    const f16_t* bp0 = hTbase + c * 1024;
    const f16_t* bp1 = bp0 + (NN / 32) * 1024;
    f16x8 b00 = *(const f16x8*)bp0;
    f16x8 b01 = *(const f16x8*)(bp0 + 128);
    f16x8 b10 = *(const f16x8*)bp1;
    f16x8 b11 = *(const f16x8*)(bp1 + 128);

    const unsigned m8 = (mc >> (quad * 8)) & 0xffu;

    // ---- phase 1: args (consumes cfc/erc/m8; all pk-f16) ----
    f16x2 arg[2][4];
#pragma unroll
    for (int p = 0; p < 4; ++p) {
      // mask folded into bias init: masked j -> -inf (exp_f16(-inf) == +0)
      HU mb;
      mb.u = (((m8 >> (2 * p)) & 1u) ? 0u : 0xFC00u) |
             (((m8 >> (2 * p + 1)) & 1u) ? 0u : 0xFC000000u);
      f16x2 bias0 = mb.h;
      f16x2 bias1 = mb.h;
#pragma unroll
      for (int f = 0; f < CF; ++f) {
        HU cu; cu.u = cfc[f][p];
        f16x2 d = cfi2h[f] - cu.h;                       // v_pk_sub_f16
        f16x2 ad = __builtin_elementwise_max(d, -d);     // v_pk_max_f16 (neg mod)
        bias0 = __builtin_elementwise_fma(ad, wch[0][f], bias0);
        bias1 = __builtin_elementwise_fma(ad, wch[1][f], bias1);
      }
#pragma unroll
      for (int h = 0; h < 2; ++h) {
        HU eu; eu.u = erc[h][p];
        f16x2 s = elh[h] + eu.h;                         // v_pk_add_f16
        f16x2 lk = __builtin_elementwise_max(s, lslope * s);
        arg[h][p] = lk + (h ? bias1 : bias0);
      }
    }

    // ---- prefetch chunk c+4 (cfc/erc/mc all consumed; one body of lead) ----
    {
      const int cn = (c + 4) & (NN / 32 - 1);
#pragma unroll
      for (int f = 0; f < CF; ++f) cfc[f] = cfb[cn * (4 * CF) + f];
#pragma unroll
      for (int h = 0; h < 2; ++h) erc[h] = erb[cn * (4 * HC) + h];
      mc = adjrow[cn];
    }

    // ---- phase 2: inline-asm f16 exp (VOP1 lo; lshr for hi; pack) ----
    union { f16x8 v; unsigned u[4]; } af[2];
#pragma unroll
    for (int p = 0; p < 4; ++p) {
#pragma unroll
      for (int h = 0; h < 2; ++h) {
        HU au; au.h = arg[h][p];
        unsigned hiu = au.u >> 16;
        unsigned r0, r1, pk;
        asm("v_exp_f16 %0, %1" : "=v"(r0) : "v"(au.u));
        asm("v_exp_f16 %0, %1" : "=v"(r1) : "v"(hiu));
        asm("v_pack_b32_f16 %0, %1, %2" : "=v"(pk) : "v"(r0), "v"(r1));
        af[h].u[p] = pk;
      }
    }

#pragma unroll
    for (int h = 0; h < 2; ++h) {
      acc[h][0] = __builtin_amdgcn_mfma_f32_16x16x32_f16(af[h].v, h ? b10 : b00, acc[h][0], 0, 0, 0);
      acc[h][1] = __builtin_amdgcn_mfma_f32_16x16x32_f16(af[h].v, h ? b11 : b01, acc[h][1], 0, 0, 0);
      Sacc[h] = __builtin_amdgcn_mfma_f32_16x16x32_f16(af[h].v, onesB, Sacc[h], 0, 0, 0);
    }
  }

  // S: D[row=quad*4+r][col] = chunk row-sum (identical across cols) ->
  // one lane per quad contributes each row
  if (il == 0) {
#pragma unroll
    for (int h = 0; h < 2; ++h)
#pragma unroll
      for (int r = 0; r < 4; ++r)
        atomicAdd(&Sbuf[quad * 4 + r][h], Sacc[h][r]);
  }
  // accumulate O partials: C/D layout row = quad*4+r (i), col = il (d half)
#pragma unroll
  for (int h = 0; h < 2; ++h)
#pragma unroll
    for (int dh = 0; dh < 2; ++dh)
#pragma unroll
      for (int r = 0; r < 4; ++r)
        atomicAdd(&Obuf[quad * 4 + r][h * DC + dh * 16 + il], acc[h][dh][r]);
  __syncthreads();

  // epilogue: divide by softmax denom, coalesced store
  for (int idx = tid; idx < 16 * 64; idx += 256) {
    int row = idx >> 6;
    int colg = idx & 63;
    out[(size_t)(ibase + row) * OC + hg * 64 + colg] =
        Obuf[row][colg] / Sbuf[row][colg >> 5];
  }
}

// ---------------------------------------------------------------------------
extern "C" void kernel_launch(void* const* d_in, const int* in_sizes, int n_in,
                              void* d_out, int out_size, void* d_ws, size_t ws_size,
                              hipStream_t stream) {
  const float* x    = (const float*)d_in[0];
  // d_in[1] = positions — unused by the reference
  const float* cfeat= (const float*)d_in[2];
  const int*   adj  = (const int*)d_in[3];
  const float* W    = (const float*)d_in[4];
  const float* a_l  = (const float*)d_in[5];
  const float* a_r  = (const float*)d_in[6];
  const float* Wc   = (const float*)d_in[7];
  const float* gate = (const float*)d_in[8];
  float* out = (float*)d_out;

  char* ws = (char*)d_ws;
  f16_t*    hT2  = (f16_t*)ws;                               // 2 MB
  unsigned* adjb = (unsigned*)(ws + (2u << 20));             // 2 MB
  float*    e_l2 = (float*)(ws + (4u << 20));                // 128 KB
  float*    cfT  = (float*)(ws + (4u << 20) + (128u << 10)); // 96 KB
  float*    Wc2  = (float*)(ws + (4u << 20) + (256u << 10)); // 192 B
  f16_t*    cfP  = (f16_t*)(ws + (4u << 20) + (320u << 10)); // 48 KB
  f16_t*    erP  = (f16_t*)(ws + (4u << 20) + (384u << 10)); // 64 KB

  prep_all<<<2560, 256, 0, stream>>>(x, W, a_l, a_r, adj, cfeat, Wc, gate,
                                     e_l2, erP, hT2, adjb, cfT, cfP, Wc2);
  attn<<<dim3(NN / 16, 4), 256, 0, stream>>>(adjb, e_l2, cfT, Wc2,
                                             (const u32x4*)cfP, (const u32x4*)erP,
                                             hT2, out);
}